// Round 1
// baseline (292.185 us; speedup 1.0000x reference)
//
#include <hip/hip_runtime.h>
#include <hip/hip_bf16.h>
#include <math.h>

// Problem constants: x[B=16][T=4096][D=512], W[512][512], v[512]
#define BB 16
#define TT 4096
#define DD 512
#define MM (BB*TT)   // 65536 rows

typedef __bf16 bf16x8 __attribute__((ext_vector_type(8)));
typedef float  f32x4  __attribute__((ext_vector_type(4)));

__device__ inline unsigned short f2bf(float f) {
    unsigned u = __builtin_bit_cast(unsigned, f) + 0x8000u;  // round-half-away
    return (unsigned short)(u >> 16);
}

// pack two fp32 -> two bf16 in one u32 (1 v_perm + 2 v_add)
__device__ inline unsigned pack_bf16x2(float lo, float hi) {
    unsigned u0 = __builtin_bit_cast(unsigned, lo) + 0x8000u;
    unsigned u1 = __builtin_bit_cast(unsigned, hi) + 0x8000u;
    return __builtin_amdgcn_perm(u1, u0, 0x07060302);  // [u1.hi16, u0.hi16]
}

// ---------------- Kernel 0: W[k][n] fp32 -> Wt[n][k] bf16 ----------------
__global__ void wt_kernel(const float* __restrict__ W, unsigned short* __restrict__ Wt) {
    int idx = blockIdx.x * 256 + threadIdx.x;   // 0..262143, coalesced writes
    int n = idx >> 9;
    int k = idx & 511;
    Wt[idx] = f2bf(W[k * DD + n]);              // strided reads absorbed by L2 (W = 1 MB)
}

// ---------------- Kernel 1: fused GEMM + tanh + v-dot -> score partials ----------------
// Tile: 128 rows x 128 cols, BK=64, 4 waves (2x2), 16x16x32 bf16 MFMA.
// spart[nt][m] = sum over this 128-col chunk of tanh(y[m,n])*v[n]
#define BM 128
#define BN 128
#define BK 64
#define LDA 72   // 64 + 8 pad (bf16 units) -> row stride 144 B = 36 banks: 2-way max (free)

__global__ __launch_bounds__(256) void scores_kernel(
        const float* __restrict__ x, const unsigned short* __restrict__ Wt,
        const float* __restrict__ v, float* __restrict__ spart) {
    __shared__ unsigned short As[BM * LDA];
    __shared__ unsigned short Bs[BN * LDA];
    __shared__ float sbuf[2][BM];

    const int tid  = threadIdx.x;
    const int m0   = blockIdx.x * BM;
    const int n0   = blockIdx.y * BN;
    const int wid  = tid >> 6;
    const int lane = tid & 63;
    const int wm   = wid >> 1;     // row half
    const int wn   = wid & 1;      // col half
    const int l15  = lane & 15;
    const int q    = lane >> 4;

    f32x4 acc[4][4];
    #pragma unroll
    for (int i = 0; i < 4; i++)
        #pragma unroll
        for (int j = 0; j < 4; j++)
            acc[i][j] = (f32x4){0.f, 0.f, 0.f, 0.f};

    for (int k0 = 0; k0 < DD; k0 += BK) {
        // Stage A: 128x64 fp32 -> bf16.  2048 float4 chunks / 256 threads = 8 each.
        #pragma unroll
        for (int i = 0; i < 8; i++) {
            int idx = i * 256 + tid;          // 0..2047
            int row = idx >> 4;               // 16 float4 per row
            int c4  = idx & 15;
            float4 f = *(const float4*)(x + (size_t)(m0 + row) * DD + k0 + c4 * 4);
            uint2 p;
            p.x = pack_bf16x2(f.x, f.y);
            p.y = pack_bf16x2(f.z, f.w);
            *(uint2*)(&As[row * LDA + c4 * 4]) = p;
        }
        // Stage B: 128 rows(n) x 64 k bf16 from Wt. 1024 16B-chunks / 256 = 4 each.
        #pragma unroll
        for (int i = 0; i < 4; i++) {
            int idx = i * 256 + tid;          // 0..1023
            int row = idx >> 3;               // 8 chunks per row
            int c8  = idx & 7;
            uint4 u = *(const uint4*)(Wt + (size_t)(n0 + row) * DD + k0 + c8 * 8);
            *(uint4*)(&Bs[row * LDA + c8 * 8]) = u;
        }
        __syncthreads();

        #pragma unroll
        for (int s = 0; s < 2; s++) {         // two 32-k steps
            const int ko = s * 32 + q * 8;
            bf16x8 a[4], b[4];
            #pragma unroll
            for (int mi = 0; mi < 4; mi++)
                a[mi] = *(const bf16x8*)(&As[(wm * 64 + mi * 16 + l15) * LDA + ko]);
            #pragma unroll
            for (int ni = 0; ni < 4; ni++)
                b[ni] = *(const bf16x8*)(&Bs[(wn * 64 + ni * 16 + l15) * LDA + ko]);
            #pragma unroll
            for (int mi = 0; mi < 4; mi++)
                #pragma unroll
                for (int ni = 0; ni < 4; ni++)
                    acc[mi][ni] = __builtin_amdgcn_mfma_f32_16x16x32_bf16(
                        a[mi], b[ni], acc[mi][ni], 0, 0, 0);
        }
        __syncthreads();
    }

    // Epilogue: tanh, dot with v over this wave's 64 cols, reduce to per-row sums.
    // C/D layout (16x16): col = lane&15, row = q*4 + r  [m89/m91 verified]
    float vv[4];
    #pragma unroll
    for (int ni = 0; ni < 4; ni++)
        vv[ni] = v[n0 + wn * 64 + ni * 16 + l15];

    #pragma unroll
    for (int mi = 0; mi < 4; mi++) {
        #pragma unroll
        for (int r = 0; r < 4; r++) {
            float sum = 0.f;
            #pragma unroll
            for (int ni = 0; ni < 4; ni++)
                sum += tanhf(acc[mi][ni][r]) * vv[ni];
            // butterfly over the 16 col-lanes
            sum += __shfl_xor(sum, 1);
            sum += __shfl_xor(sum, 2);
            sum += __shfl_xor(sum, 4);
            sum += __shfl_xor(sum, 8);
            if (l15 == 0)
                sbuf[wn][wm * 64 + mi * 16 + q * 4 + r] = sum;
        }
    }
    __syncthreads();
    if (tid < BM)
        spart[(size_t)blockIdx.y * MM + m0 + tid] = sbuf[0][tid] + sbuf[1][tid];
}

// ---------------- Kernel 2: softmax over T per batch ----------------
__global__ void softmax_kernel(const float* __restrict__ spart, float* __restrict__ weights) {
    const int b = blockIdx.x;
    const int tid = threadIdx.x;     // 256 threads, 16 elems each
    __shared__ float wred[4];

    float s[16];
    float mx = -1e30f;
    #pragma unroll
    for (int i = 0; i < 16; i++) {
        int t = b * TT + i * 256 + tid;
        float sv = spart[t] + spart[MM + t] + spart[2 * MM + t] + spart[3 * MM + t];
        s[i] = sv;
        mx = fmaxf(mx, sv);
    }
    #pragma unroll
    for (int off = 32; off; off >>= 1) mx = fmaxf(mx, __shfl_xor(mx, off));
    if ((tid & 63) == 0) wred[tid >> 6] = mx;
    __syncthreads();
    mx = fmaxf(fmaxf(wred[0], wred[1]), fmaxf(wred[2], wred[3]));
    __syncthreads();

    float sum = 0.f;
    #pragma unroll
    for (int i = 0; i < 16; i++) { s[i] = __expf(s[i] - mx); sum += s[i]; }
    #pragma unroll
    for (int off = 32; off; off >>= 1) sum += __shfl_xor(sum, off);
    if ((tid & 63) == 0) wred[tid >> 6] = sum;
    __syncthreads();
    sum = wred[0] + wred[1] + wred[2] + wred[3];

    const float inv = 1.0f / sum;
    #pragma unroll
    for (int i = 0; i < 16; i++)
        weights[b * TT + i * 256 + tid] = s[i] * inv;
}

// ---------------- Kernel 3: out[b,d] = sum_t w[b,t] * x[b,t,d] ----------------
#define TCH 128
__global__ void pool_kernel(const float* __restrict__ x, const float* __restrict__ weights,
                            float* __restrict__ out) {
    __shared__ float wsm[TCH];
    const int b  = blockIdx.y;
    const int t0 = blockIdx.x * TCH;
    const int tid = threadIdx.x;
    if (tid < TCH) wsm[tid] = weights[b * TT + t0 + tid];
    __syncthreads();

    float2 acc = {0.f, 0.f};
    const float* xp = x + ((size_t)b * TT + t0) * DD + tid * 2;
    #pragma unroll 4
    for (int t = 0; t < TCH; t++) {
        float2 xv = *(const float2*)(xp + (size_t)t * DD);
        float w = wsm[t];
        acc.x += w * xv.x;
        acc.y += w * xv.y;
    }
    atomicAdd(&out[b * DD + tid * 2],     acc.x);
    atomicAdd(&out[b * DD + tid * 2 + 1], acc.y);
}

extern "C" void kernel_launch(void* const* d_in, const int* in_sizes, int n_in,
                              void* d_out, int out_size, void* d_ws, size_t ws_size,
                              hipStream_t stream) {
    (void)in_sizes; (void)n_in; (void)out_size; (void)ws_size;
    const float* x = (const float*)d_in[0];
    const float* W = (const float*)d_in[1];
    const float* v = (const float*)d_in[2];
    float* out = (float*)d_out;

    // ws layout: Wt bf16 (512 KB) | spart fp32 4x65536 (1 MB) | weights fp32 (256 KB)
    unsigned short* Wt    = (unsigned short*)d_ws;
    float* spart          = (float*)((char*)d_ws + 512 * 1024);
    float* weights        = (float*)((char*)d_ws + 512 * 1024 + 1024 * 1024);

    hipMemsetAsync(d_out, 0, BB * DD * sizeof(float), stream);

    wt_kernel<<<DD * DD / 256, 256, 0, stream>>>(W, Wt);

    dim3 g1(MM / BM, DD / BN);   // 512 x 4
    scores_kernel<<<g1, 256, 0, stream>>>(x, Wt, v, spart);

    softmax_kernel<<<BB, 256, 0, stream>>>(spart, weights);

    pool_kernel<<<dim3(TT / TCH, BB), 256, 0, stream>>>(x, weights, out);
}

// Round 2
// 289.390 us; speedup vs baseline: 1.0097x; 1.0097x over previous
//
#include <hip/hip_runtime.h>
#include <hip/hip_bf16.h>
#include <math.h>

// Problem constants: x[B=16][T=4096][D=512], W[512][512], v[512]
#define BB 16
#define TT 4096
#define DD 512
#define MM (BB*TT)   // 65536 rows

typedef __bf16 bf16x8 __attribute__((ext_vector_type(8)));
typedef float  f32x4  __attribute__((ext_vector_type(4)));

__device__ inline unsigned short f2bf(float f) {
    unsigned u = __builtin_bit_cast(unsigned, f) + 0x8000u;  // round-half-away
    return (unsigned short)(u >> 16);
}

// pack two fp32 -> two bf16 in one u32 (1 v_perm + 2 v_add)
__device__ inline unsigned pack_bf16x2(float lo, float hi) {
    unsigned u0 = __builtin_bit_cast(unsigned, lo) + 0x8000u;
    unsigned u1 = __builtin_bit_cast(unsigned, hi) + 0x8000u;
    return __builtin_amdgcn_perm(u1, u0, 0x07060302);  // [u1.hi16, u0.hi16]
}

// async global -> LDS, 16 B per lane. LDS dest is wave-uniform base + lane*16.
__device__ inline void gld_lds16(const unsigned short* g, unsigned short* l) {
    __builtin_amdgcn_global_load_lds(
        (const __attribute__((address_space(1))) unsigned int*)(const void*)g,
        (__attribute__((address_space(3))) unsigned int*)(void*)l, 16, 0, 0);
}

// ---------------- Kernel: x fp32 -> xb bf16 (coalesced, 8 elems/thread) ----------------
__global__ void cast_kernel(const float* __restrict__ x, unsigned short* __restrict__ xb) {
    size_t i = (size_t)(blockIdx.x * 256 + threadIdx.x) * 8;
    float4 f0 = *(const float4*)(x + i);
    float4 f1 = *(const float4*)(x + i + 4);
    uint4 o;
    o.x = pack_bf16x2(f0.x, f0.y);
    o.y = pack_bf16x2(f0.z, f0.w);
    o.z = pack_bf16x2(f1.x, f1.y);
    o.w = pack_bf16x2(f1.z, f1.w);
    *(uint4*)(xb + i) = o;
}

// ---------------- Kernel: W[k][n] fp32 -> Wt[n][k] bf16 ----------------
__global__ void wt_kernel(const float* __restrict__ W, unsigned short* __restrict__ Wt) {
    int idx = blockIdx.x * 256 + threadIdx.x;   // coalesced writes
    int n = idx >> 9;
    int k = idx & 511;
    Wt[idx] = f2bf(W[k * DD + n]);              // strided reads absorbed by L2 (W = 1 MB)
}

// ---------------- Fused GEMM + tanh + v-dot (bf16 staging, global_load_lds) ----------------
// Tile: 128x128, BK=64, 4 waves (2x2), 16x16x32 bf16 MFMA.
// LDS tiles are UNPADDED 128 rows x 64 cols bf16 (row = 128 B = 32 banks), with an
// XOR swizzle on the 16B-chunk index: LDS chunk cc of row r holds global chunk cc^(r&7).
// Staging (global_load_lds) writes lane-contiguous 1024 B per wave (conflict-free);
// MFMA-side ds_read_b128 then lands exactly 8 words/bank (balanced minimum).
#define BM 128
#define BN 128
#define BK 64

__global__ __launch_bounds__(256) void scores_bf16_kernel(
        const unsigned short* __restrict__ xb, const unsigned short* __restrict__ Wt,
        const float* __restrict__ v, float* __restrict__ spart) {
    __shared__ unsigned short As[BM * BK];   // 16 KB
    __shared__ unsigned short Bs[BN * BK];   // 16 KB
    __shared__ float sbuf[2][BM];

    const int tid  = threadIdx.x;
    const int m0   = blockIdx.x * BM;
    const int n0   = blockIdx.y * BN;
    const int wid  = tid >> 6;
    const int lane = tid & 63;
    const int wm   = wid >> 1;     // row half
    const int wn   = wid & 1;      // col half
    const int l15  = lane & 15;
    const int q    = lane >> 4;

    // staging geometry: per wave 4 issues x 64 lanes x 16 B covers 32 rows x 64 cols
    int srow[4], scol[4];
    #pragma unroll
    for (int i = 0; i < 4; i++) {
        int ci = (wid * 4 + i) * 64 + lane;      // linear 16B-chunk index 0..1023
        srow[i] = ci >> 3;                       // 8 chunks per row
        scol[i] = ((ci & 7) ^ (srow[i] & 7)) * 8;  // inverse-swizzled global col (elems)
    }

    f32x4 acc[4][4];
    #pragma unroll
    for (int i = 0; i < 4; i++)
        #pragma unroll
        for (int j = 0; j < 4; j++)
            acc[i][j] = (f32x4){0.f, 0.f, 0.f, 0.f};

    for (int k0 = 0; k0 < DD; k0 += BK) {
        #pragma unroll
        for (int i = 0; i < 4; i++) {
            gld_lds16(xb + (size_t)(m0 + srow[i]) * DD + k0 + scol[i],
                      &As[(wid * 4 + i) * 512]);
            gld_lds16(Wt + (size_t)(n0 + srow[i]) * DD + k0 + scol[i],
                      &Bs[(wid * 4 + i) * 512]);
        }
        __syncthreads();   // compiler drains vmcnt before s_barrier

        #pragma unroll
        for (int s = 0; s < 2; s++) {            // two 32-k steps
            const int c = s * 4 + q;             // logical 16B chunk within row
            bf16x8 a[4], b[4];
            #pragma unroll
            for (int mi = 0; mi < 4; mi++) {
                int R = wm * 64 + mi * 16 + l15;
                a[mi] = *(const bf16x8*)(&As[R * BK + ((c ^ (R & 7)) * 8)]);
            }
            #pragma unroll
            for (int ni = 0; ni < 4; ni++) {
                int R = wn * 64 + ni * 16 + l15;
                b[ni] = *(const bf16x8*)(&Bs[R * BK + ((c ^ (R & 7)) * 8)]);
            }
            #pragma unroll
            for (int mi = 0; mi < 4; mi++)
                #pragma unroll
                for (int ni = 0; ni < 4; ni++)
                    acc[mi][ni] = __builtin_amdgcn_mfma_f32_16x16x32_bf16(
                        a[mi], b[ni], acc[mi][ni], 0, 0, 0);
        }
        __syncthreads();
    }

    // Epilogue: tanh, dot with v, reduce to per-row sums.
    // C/D layout (16x16): col = lane&15, row = q*4 + r  [m89/m91 verified]
    float vv[4];
    #pragma unroll
    for (int ni = 0; ni < 4; ni++)
        vv[ni] = v[n0 + wn * 64 + ni * 16 + l15];

    #pragma unroll
    for (int mi = 0; mi < 4; mi++) {
        #pragma unroll
        for (int r = 0; r < 4; r++) {
            float sum = 0.f;
            #pragma unroll
            for (int ni = 0; ni < 4; ni++)
                sum += tanhf(acc[mi][ni][r]) * vv[ni];
            sum += __shfl_xor(sum, 1);
            sum += __shfl_xor(sum, 2);
            sum += __shfl_xor(sum, 4);
            sum += __shfl_xor(sum, 8);
            if (l15 == 0)
                sbuf[wn][wm * 64 + mi * 16 + q * 4 + r] = sum;
        }
    }
    __syncthreads();
    if (tid < BM)
        spart[(size_t)blockIdx.y * MM + m0 + tid] = sbuf[0][tid] + sbuf[1][tid];
}

// ---------------- Fallback fused GEMM (fp32 staging, round-1 proven) ----------------
#define LDA 72
__global__ __launch_bounds__(256) void scores_f32_kernel(
        const float* __restrict__ x, const unsigned short* __restrict__ Wt,
        const float* __restrict__ v, float* __restrict__ spart) {
    __shared__ unsigned short As[BM * LDA];
    __shared__ unsigned short Bs[BN * LDA];
    __shared__ float sbuf[2][BM];

    const int tid  = threadIdx.x;
    const int m0   = blockIdx.x * BM;
    const int n0   = blockIdx.y * BN;
    const int wid  = tid >> 6;
    const int lane = tid & 63;
    const int wm   = wid >> 1;
    const int wn   = wid & 1;
    const int l15  = lane & 15;
    const int q    = lane >> 4;

    f32x4 acc[4][4];
    #pragma unroll
    for (int i = 0; i < 4; i++)
        #pragma unroll
        for (int j = 0; j < 4; j++)
            acc[i][j] = (f32x4){0.f, 0.f, 0.f, 0.f};

    for (int k0 = 0; k0 < DD; k0 += BK) {
        #pragma unroll
        for (int i = 0; i < 8; i++) {
            int idx = i * 256 + tid;
            int row = idx >> 4;
            int c4  = idx & 15;
            float4 f = *(const float4*)(x + (size_t)(m0 + row) * DD + k0 + c4 * 4);
            uint2 p;
            p.x = pack_bf16x2(f.x, f.y);
            p.y = pack_bf16x2(f.z, f.w);
            *(uint2*)(&As[row * LDA + c4 * 4]) = p;
        }
        #pragma unroll
        for (int i = 0; i < 4; i++) {
            int idx = i * 256 + tid;
            int row = idx >> 3;
            int c8  = idx & 7;
            uint4 u = *(const uint4*)(Wt + (size_t)(n0 + row) * DD + k0 + c8 * 8);
            *(uint4*)(&Bs[row * LDA + c8 * 8]) = u;
        }
        __syncthreads();

        #pragma unroll
        for (int s = 0; s < 2; s++) {
            const int ko = s * 32 + q * 8;
            bf16x8 a[4], b[4];
            #pragma unroll
            for (int mi = 0; mi < 4; mi++)
                a[mi] = *(const bf16x8*)(&As[(wm * 64 + mi * 16 + l15) * LDA + ko]);
            #pragma unroll
            for (int ni = 0; ni < 4; ni++)
                b[ni] = *(const bf16x8*)(&Bs[(wn * 64 + ni * 16 + l15) * LDA + ko]);
            #pragma unroll
            for (int mi = 0; mi < 4; mi++)
                #pragma unroll
                for (int ni = 0; ni < 4; ni++)
                    acc[mi][ni] = __builtin_amdgcn_mfma_f32_16x16x32_bf16(
                        a[mi], b[ni], acc[mi][ni], 0, 0, 0);
        }
        __syncthreads();
    }

    float vv[4];
    #pragma unroll
    for (int ni = 0; ni < 4; ni++)
        vv[ni] = v[n0 + wn * 64 + ni * 16 + l15];

    #pragma unroll
    for (int mi = 0; mi < 4; mi++) {
        #pragma unroll
        for (int r = 0; r < 4; r++) {
            float sum = 0.f;
            #pragma unroll
            for (int ni = 0; ni < 4; ni++)
                sum += tanhf(acc[mi][ni][r]) * vv[ni];
            sum += __shfl_xor(sum, 1);
            sum += __shfl_xor(sum, 2);
            sum += __shfl_xor(sum, 4);
            sum += __shfl_xor(sum, 8);
            if (l15 == 0)
                sbuf[wn][wm * 64 + mi * 16 + q * 4 + r] = sum;
        }
    }
    __syncthreads();
    if (tid < BM)
        spart[(size_t)blockIdx.y * MM + m0 + tid] = sbuf[0][tid] + sbuf[1][tid];
}

// ---------------- Softmax over T per batch ----------------
__global__ void softmax_kernel(const float* __restrict__ spart, float* __restrict__ weights) {
    const int b = blockIdx.x;
    const int tid = threadIdx.x;     // 256 threads, 16 elems each
    __shared__ float wred[4];

    float s[16];
    float mx = -1e30f;
    #pragma unroll
    for (int i = 0; i < 16; i++) {
        int t = b * TT + i * 256 + tid;
        float sv = spart[t] + spart[MM + t] + spart[2 * MM + t] + spart[3 * MM + t];
        s[i] = sv;
        mx = fmaxf(mx, sv);
    }
    #pragma unroll
    for (int off = 32; off; off >>= 1) mx = fmaxf(mx, __shfl_xor(mx, off));
    if ((tid & 63) == 0) wred[tid >> 6] = mx;
    __syncthreads();
    mx = fmaxf(fmaxf(wred[0], wred[1]), fmaxf(wred[2], wred[3]));
    __syncthreads();

    float sum = 0.f;
    #pragma unroll
    for (int i = 0; i < 16; i++) { s[i] = __expf(s[i] - mx); sum += s[i]; }
    #pragma unroll
    for (int off = 32; off; off >>= 1) sum += __shfl_xor(sum, off);
    if ((tid & 63) == 0) wred[tid >> 6] = sum;
    __syncthreads();
    sum = wred[0] + wred[1] + wred[2] + wred[3];

    const float inv = 1.0f / sum;
    #pragma unroll
    for (int i = 0; i < 16; i++)
        weights[b * TT + i * 256 + tid] = s[i] * inv;
}

// ---------------- Pooling: out[b,d] = sum_t w[b,t] * x[b,t,d] ----------------
#define TCH 128
__global__ void pool_bf16_kernel(const unsigned short* __restrict__ xb,
                                 const float* __restrict__ weights, float* __restrict__ out) {
    __shared__ float wsm[TCH];
    const int b  = blockIdx.y;
    const int t0 = blockIdx.x * TCH;
    const int tid = threadIdx.x;
    if (tid < TCH) wsm[tid] = weights[b * TT + t0 + tid];
    __syncthreads();

    float2 acc = {0.f, 0.f};
    const unsigned short* xp = xb + ((size_t)b * TT + t0) * DD + tid * 2;
    #pragma unroll 4
    for (int t = 0; t < TCH; t++) {
        unsigned u = *(const unsigned*)(xp + (size_t)t * DD);
        float lo = __builtin_bit_cast(float, u << 16);
        float hi = __builtin_bit_cast(float, u & 0xFFFF0000u);
        float w = wsm[t];
        acc.x += w * lo;
        acc.y += w * hi;
    }
    atomicAdd(&out[b * DD + tid * 2],     acc.x);
    atomicAdd(&out[b * DD + tid * 2 + 1], acc.y);
}

__global__ void pool_f32_kernel(const float* __restrict__ x, const float* __restrict__ weights,
                                float* __restrict__ out) {
    __shared__ float wsm[TCH];
    const int b  = blockIdx.y;
    const int t0 = blockIdx.x * TCH;
    const int tid = threadIdx.x;
    if (tid < TCH) wsm[tid] = weights[b * TT + t0 + tid];
    __syncthreads();

    float2 acc = {0.f, 0.f};
    const float* xp = x + ((size_t)b * TT + t0) * DD + tid * 2;
    #pragma unroll 4
    for (int t = 0; t < TCH; t++) {
        float2 xv = *(const float2*)(xp + (size_t)t * DD);
        float w = wsm[t];
        acc.x += w * xv.x;
        acc.y += w * xv.y;
    }
    atomicAdd(&out[b * DD + tid * 2],     acc.x);
    atomicAdd(&out[b * DD + tid * 2 + 1], acc.y);
}

extern "C" void kernel_launch(void* const* d_in, const int* in_sizes, int n_in,
                              void* d_out, int out_size, void* d_ws, size_t ws_size,
                              hipStream_t stream) {
    (void)in_sizes; (void)n_in; (void)out_size;
    const float* x = (const float*)d_in[0];
    const float* W = (const float*)d_in[1];
    const float* v = (const float*)d_in[2];
    float* out = (float*)d_out;

    const size_t XB_BYTES = (size_t)MM * DD * 2;               // 64 MB
    const size_t NEED = XB_BYTES + 512*1024 + 1024*1024 + 256*1024;

    hipMemsetAsync(d_out, 0, BB * DD * sizeof(float), stream);

    if (ws_size >= NEED) {
        unsigned short* xb   = (unsigned short*)d_ws;
        unsigned short* Wt   = (unsigned short*)((char*)d_ws + XB_BYTES);
        float* spart         = (float*)((char*)d_ws + XB_BYTES + 512*1024);
        float* weights       = (float*)((char*)d_ws + XB_BYTES + 512*1024 + 1024*1024);

        wt_kernel<<<DD * DD / 256, 256, 0, stream>>>(W, Wt);
        cast_kernel<<<(size_t)MM * DD / 8 / 256, 256, 0, stream>>>(x, xb);

        dim3 g1(MM / BM, DD / BN);   // 512 x 4
        scores_bf16_kernel<<<g1, 256, 0, stream>>>(xb, Wt, v, spart);
        softmax_kernel<<<BB, 256, 0, stream>>>(spart, weights);
        pool_bf16_kernel<<<dim3(TT / TCH, BB), 256, 0, stream>>>(xb, weights, out);
    } else {
        unsigned short* Wt   = (unsigned short*)d_ws;
        float* spart         = (float*)((char*)d_ws + 512*1024);
        float* weights       = (float*)((char*)d_ws + 512*1024 + 1024*1024);

        wt_kernel<<<DD * DD / 256, 256, 0, stream>>>(W, Wt);
        dim3 g1(MM / BM, DD / BN);
        scores_f32_kernel<<<g1, 256, 0, stream>>>(x, Wt, v, spart);
        softmax_kernel<<<BB, 256, 0, stream>>>(spart, weights);
        pool_f32_kernel<<<dim3(TT / TCH, BB), 256, 0, stream>>>(x, weights, out);
    }
}

// Round 3
// 288.516 us; speedup vs baseline: 1.0127x; 1.0030x over previous
//
#include <hip/hip_runtime.h>
#include <hip/hip_bf16.h>
#include <math.h>

// Problem constants: x[B=16][T=4096][D=512], W[512][512], v[512]
#define BB 16
#define TT 4096
#define DD 512
#define MM (BB*TT)   // 65536 rows

typedef __bf16 bf16x8 __attribute__((ext_vector_type(8)));
typedef float  f32x4  __attribute__((ext_vector_type(4)));

__device__ inline unsigned short f2bf(float f) {
    unsigned u = __builtin_bit_cast(unsigned, f) + 0x8000u;  // round-half-away
    return (unsigned short)(u >> 16);
}

// pack two fp32 -> two bf16 in one u32 (2 v_add + 1 v_perm)
__device__ inline unsigned pack_bf16x2(float lo, float hi) {
    unsigned u0 = __builtin_bit_cast(unsigned, lo) + 0x8000u;
    unsigned u1 = __builtin_bit_cast(unsigned, hi) + 0x8000u;
    return __builtin_amdgcn_perm(u1, u0, 0x07060302);  // [u1.hi16, u0.hi16]
}

// fast tanh: 1 - 2/(e^{2y}+1).  |y| <~ 1.5 here, no overflow concerns.
__device__ inline float tanh_fast(float y) {
    float e = __expf(2.0f * y);
    return 1.0f - 2.0f * __builtin_amdgcn_rcpf(e + 1.0f);
}

// ---------------- Kernel: W[k][n] fp32 -> Wt[n][k] bf16 ----------------
__global__ void wt_kernel(const float* __restrict__ W, unsigned short* __restrict__ Wt) {
    int idx = blockIdx.x * 256 + threadIdx.x;   // coalesced writes
    int n = idx >> 9;
    int k = idx & 511;
    Wt[idx] = f2bf(W[k * DD + n]);              // strided reads absorbed by L2 (W = 1 MB)
}

// ---------------- Fused GEMM + tanh + v-dot -> final scores ----------------
// Block = 64 rows x full N=512 x full K=512.  4 waves; wave w owns cols [w*128, w*128+128)
// as 2 passes of a 64x64 accumulator (4x4 16x16x32 MFMA tiles, full-K accumulation).
// A-strip (64x512 bf16 = 64 KB) staged once into LDS (fp32->bf16 convert, XOR chunk
// swizzle for conflict-free ds_read_b128).  B (Wt) read directly global->VGPR
// (L2-resident, immediate offsets).  ZERO barriers in the K-loop.
__global__ __launch_bounds__(256, 2) void scores_kernel(
        const float* __restrict__ x, const unsigned short* __restrict__ Wt,
        const float* __restrict__ v, float* __restrict__ scores) {
    __shared__ unsigned short As[64 * DD];   // 64 KB
    __shared__ float sbuf[4][64];

    const int tid  = threadIdx.x;
    const int m0   = blockIdx.x * 64;
    const int wid  = tid >> 6;
    const int lane = tid & 63;
    const int l15  = lane & 15;
    const int q    = lane >> 4;
    const int r3   = l15 & 7;

    // ---- Stage A: 64 rows x 512 cols fp32 -> bf16, swizzled. 16 iters x 32 B/thread.
    // Wave-iter = one full row (64 lanes x 32 B = 2 KB contiguous global read).
    #pragma unroll
    for (int i = 0; i < 16; i++) {
        int u = i * 256 + tid;           // 0..4095 (16-B output chunk id)
        int r = u >> 6;                  // 64 chunks per row
        int c = u & 63;
        const float* gp = x + (size_t)(m0 + r) * DD + c * 8;
        float4 f0 = *(const float4*)(gp);
        float4 f1 = *(const float4*)(gp + 4);
        uint4 o;
        o.x = pack_bf16x2(f0.x, f0.y);
        o.y = pack_bf16x2(f0.z, f0.w);
        o.z = pack_bf16x2(f1.x, f1.y);
        o.w = pack_bf16x2(f1.z, f1.w);
        *(uint4*)(&As[r * DD + (c ^ (r & 7)) * 8]) = o;
    }
    __syncthreads();   // the only barrier before the epilogue

    float vpart[4][4];
    #pragma unroll
    for (int mi = 0; mi < 4; mi++)
        #pragma unroll
        for (int rr = 0; rr < 4; rr++)
            vpart[mi][rr] = 0.f;

    // A-frag LDS address (ushort units): row R = mi*16+l15, k-step s, quarter q
    //   chunk = (s*4+q) ^ r3  (XOR swizzle); addr = R*512 + chunk*8
    #define A_FRAG(mi, s) (*(const bf16x8*)(&As[((mi)*16 + l15) * DD + ((((s)*4 + q) ^ r3) * 8)]))

    #pragma unroll
    for (int p = 0; p < 2; p++) {
        const int n0 = wid * 128 + p * 64;

        // B fragment base pointers: row n = n0+ni*16+l15, k offset q*8; step stride 32 elems
        const unsigned short* bp[4];
        #pragma unroll
        for (int ni = 0; ni < 4; ni++)
            bp[ni] = Wt + (size_t)(n0 + ni * 16 + l15) * DD + q * 8;

        f32x4 acc[4][4];
        #pragma unroll
        for (int mi = 0; mi < 4; mi++)
            #pragma unroll
            for (int ni = 0; ni < 4; ni++)
                acc[mi][ni] = (f32x4){0.f, 0.f, 0.f, 0.f};

        bf16x8 a[2][4], b[3][4];
        #pragma unroll
        for (int mi = 0; mi < 4; mi++) a[0][mi] = A_FRAG(mi, 0);
        #pragma unroll
        for (int ni = 0; ni < 4; ni++) {
            b[0][ni] = *(const bf16x8*)(bp[ni]);
            b[1][ni] = *(const bf16x8*)(bp[ni] + 32);
        }

        #pragma unroll
        for (int s = 0; s < 16; s++) {
            const int cur = s & 1;
            if (s < 15) {
                #pragma unroll
                for (int mi = 0; mi < 4; mi++) a[cur ^ 1][mi] = A_FRAG(mi, s + 1);
            }
            if (s < 14) {
                #pragma unroll
                for (int ni = 0; ni < 4; ni++)
                    b[(s + 2) % 3][ni] = *(const bf16x8*)(bp[ni] + (s + 2) * 32);
            }
            #pragma unroll
            for (int mi = 0; mi < 4; mi++)
                #pragma unroll
                for (int ni = 0; ni < 4; ni++)
                    acc[mi][ni] = __builtin_amdgcn_mfma_f32_16x16x32_bf16(
                        a[cur][mi], b[s % 3][ni], acc[mi][ni], 0, 0, 0);
        }

        // epilogue: tanh + v-dot into per-row partials
        // C/D layout (16x16): col = lane&15, row = q*4 + rr  [m89/m91 verified]
        float vv[4];
        #pragma unroll
        for (int ni = 0; ni < 4; ni++)
            vv[ni] = v[n0 + ni * 16 + l15];
        #pragma unroll
        for (int mi = 0; mi < 4; mi++)
            #pragma unroll
            for (int ni = 0; ni < 4; ni++)
                #pragma unroll
                for (int rr = 0; rr < 4; rr++)
                    vpart[mi][rr] += tanh_fast(acc[mi][ni][rr]) * vv[ni];
    }
    #undef A_FRAG

    // cross-lane reduce over the 16 col-lanes, then cross-wave via LDS
    #pragma unroll
    for (int mi = 0; mi < 4; mi++)
        #pragma unroll
        for (int rr = 0; rr < 4; rr++) {
            float sum = vpart[mi][rr];
            sum += __shfl_xor(sum, 1);
            sum += __shfl_xor(sum, 2);
            sum += __shfl_xor(sum, 4);
            sum += __shfl_xor(sum, 8);
            if (l15 == 0)
                sbuf[wid][mi * 16 + q * 4 + rr] = sum;
        }
    __syncthreads();
    if (tid < 64)
        scores[m0 + tid] = sbuf[0][tid] + sbuf[1][tid] + sbuf[2][tid] + sbuf[3][tid];
}

// ---------------- Softmax over T per batch ----------------
__global__ void softmax_kernel(const float* __restrict__ scores, float* __restrict__ weights) {
    const int b = blockIdx.x;
    const int tid = threadIdx.x;     // 256 threads, 16 elems each
    __shared__ float wred[4];

    float s[16];
    float mx = -1e30f;
    #pragma unroll
    for (int i = 0; i < 16; i++) {
        float sv = scores[b * TT + i * 256 + tid];
        s[i] = sv;
        mx = fmaxf(mx, sv);
    }
    #pragma unroll
    for (int off = 32; off; off >>= 1) mx = fmaxf(mx, __shfl_xor(mx, off));
    if ((tid & 63) == 0) wred[tid >> 6] = mx;
    __syncthreads();
    mx = fmaxf(fmaxf(wred[0], wred[1]), fmaxf(wred[2], wred[3]));
    __syncthreads();

    float sum = 0.f;
    #pragma unroll
    for (int i = 0; i < 16; i++) { s[i] = __expf(s[i] - mx); sum += s[i]; }
    #pragma unroll
    for (int off = 32; off; off >>= 1) sum += __shfl_xor(sum, off);
    if ((tid & 63) == 0) wred[tid >> 6] = sum;
    __syncthreads();
    sum = wred[0] + wred[1] + wred[2] + wred[3];

    const float inv = 1.0f / sum;
    #pragma unroll
    for (int i = 0; i < 16; i++)
        weights[b * TT + i * 256 + tid] = s[i] * inv;
}

// ---------------- Pooling: out[b,d] = sum_t w[b,t] * x[b,t,d] ----------------
#define TCH 128
__global__ void pool_kernel(const float* __restrict__ x, const float* __restrict__ weights,
                            float* __restrict__ out) {
    __shared__ float wsm[TCH];
    const int b  = blockIdx.y;
    const int t0 = blockIdx.x * TCH;
    const int tid = threadIdx.x;
    if (tid < TCH) wsm[tid] = weights[b * TT + t0 + tid];
    __syncthreads();

    float2 acc = {0.f, 0.f};
    const float* xp = x + ((size_t)b * TT + t0) * DD + tid * 2;
    #pragma unroll 4
    for (int t = 0; t < TCH; t++) {
        float2 xv = *(const float2*)(xp + (size_t)t * DD);
        float w = wsm[t];
        acc.x += w * xv.x;
        acc.y += w * xv.y;
    }
    atomicAdd(&out[b * DD + tid * 2],     acc.x);
    atomicAdd(&out[b * DD + tid * 2 + 1], acc.y);
}

extern "C" void kernel_launch(void* const* d_in, const int* in_sizes, int n_in,
                              void* d_out, int out_size, void* d_ws, size_t ws_size,
                              hipStream_t stream) {
    (void)in_sizes; (void)n_in; (void)out_size; (void)ws_size;
    const float* x = (const float*)d_in[0];
    const float* W = (const float*)d_in[1];
    const float* v = (const float*)d_in[2];
    float* out = (float*)d_out;

    // ws layout: Wt bf16 (512 KB) | scores fp32 (256 KB) | weights fp32 (256 KB)
    unsigned short* Wt = (unsigned short*)d_ws;
    float* scores      = (float*)((char*)d_ws + 512 * 1024);
    float* weights     = (float*)((char*)d_ws + 512 * 1024 + 256 * 1024);

    hipMemsetAsync(d_out, 0, BB * DD * sizeof(float), stream);

    wt_kernel<<<DD * DD / 256, 256, 0, stream>>>(W, Wt);

    scores_kernel<<<MM / 64, 256, 0, stream>>>(x, Wt, v, scores);

    softmax_kernel<<<BB, 256, 0, stream>>>(scores, weights);

    pool_kernel<<<dim3(TT / TCH, BB), 256, 0, stream>>>(x, weights, out);
}